// Round 1
// baseline (513.919 us; speedup 1.0000x reference)
//
#include <hip/hip_runtime.h>
#include <cmath>
#include <cstdint>

typedef __bf16 bf16;
typedef __bf16 bf16x8 __attribute__((ext_vector_type(8)));
typedef __bf16 bf16x4 __attribute__((ext_vector_type(4)));
typedef float  f32x4  __attribute__((ext_vector_type(4)));

#define M_TOK 8192
#define SCALE_ 0.10206207261596575f   // 96^-0.5

__device__ __forceinline__ void gld_lds16(const void* g, void* l) {
  __builtin_amdgcn_global_load_lds(
      (__attribute__((address_space(1))) void*)(uintptr_t)g,
      (__attribute__((address_space(3))) void*)(uintptr_t)l,
      16, 0, 0);
}

__device__ __forceinline__ float gelu_f(float x) {
  return 0.5f * x * (1.0f + erff(x * 0.7071067811865475f));
}

// ---------------- weight transpose + cast: w (K x N f32) -> wt (N x K bf16) ----
__global__ __launch_bounds__(256) void transpose_cast_kernel(
    const float* __restrict__ w, bf16* __restrict__ wt, int K, int N) {
  __shared__ float tile[32][33];
  int tx = threadIdx.x, ty = threadIdx.y;
  int nt = blockIdx.x * 32, kt = blockIdx.y * 32;
#pragma unroll
  for (int i = ty; i < 32; i += 8)
    tile[i][tx] = w[(size_t)(kt + i) * N + nt + tx];
  __syncthreads();
#pragma unroll
  for (int i = ty; i < 32; i += 8)
    wt[(size_t)(nt + i) * K + kt + tx] = (bf16)tile[tx][i];
}

// ---------------- layernorm: row of 768, one wave per row ---------------------
template <int OB>
__global__ __launch_bounds__(256) void ln_kernel(
    const float* __restrict__ x, const float* __restrict__ g,
    const float* __restrict__ b, bf16* __restrict__ ob, float* __restrict__ of) {
  int w = threadIdx.x >> 6, lane = threadIdx.x & 63;
  size_t row = (size_t)blockIdx.x * 4 + w;
  const float* xr = x + row * 768;
  float4 v[3];
  float s = 0.f, sq = 0.f;
#pragma unroll
  for (int k = 0; k < 3; k++) {
    v[k] = *(const float4*)(xr + (k * 64 + lane) * 4);
    s += v[k].x + v[k].y + v[k].z + v[k].w;
    sq += v[k].x * v[k].x + v[k].y * v[k].y + v[k].z * v[k].z + v[k].w * v[k].w;
  }
#pragma unroll
  for (int off = 32; off >= 1; off >>= 1) {
    s += __shfl_xor(s, off);
    sq += __shfl_xor(sq, off);
  }
  float mean = s * (1.f / 768.f);
  float rstd = rsqrtf(sq * (1.f / 768.f) - mean * mean + 1e-5f);
#pragma unroll
  for (int k = 0; k < 3; k++) {
    int c = (k * 64 + lane) * 4;
    float4 gg = *(const float4*)(g + c);
    float4 bb = *(const float4*)(b + c);
    float o0 = (v[k].x - mean) * rstd * gg.x + bb.x;
    float o1 = (v[k].y - mean) * rstd * gg.y + bb.y;
    float o2 = (v[k].z - mean) * rstd * gg.z + bb.z;
    float o3 = (v[k].w - mean) * rstd * gg.w + bb.w;
    if (OB) {
      bf16x4 pk = {(bf16)o0, (bf16)o1, (bf16)o2, (bf16)o3};
      *(bf16x4*)(ob + row * 768 + c) = pk;
    } else {
      float4 ov = {o0, o1, o2, o3};
      *(float4*)(of + row * 768 + c) = ov;
    }
  }
}

// ---------------- split qkv -> q[bh][n][dh], k[bh][n][dh], vt[bh][dh][n] ------
__global__ __launch_bounds__(256) void split_qkv_kernel(
    const bf16* __restrict__ qkv, bf16* __restrict__ q, bf16* __restrict__ k,
    bf16* __restrict__ vt) {
  int idx = blockIdx.x * 256 + threadIdx.x;  // over 8192 * 288
  int row = idx / 288;                       // token = b*1024 + n
  int c = (idx % 288) * 8;
  int which = c / 768;
  int h = (c % 768) / 96;
  int dh = c % 96;
  int b = row >> 10, n = row & 1023;
  bf16x8 v = *(const bf16x8*)(qkv + (size_t)row * 2304 + c);
  int bh = b * 8 + h;
  if (which == 0) {
    *(bf16x8*)(q + ((size_t)bh * 1024 + n) * 96 + dh) = v;
  } else if (which == 1) {
    *(bf16x8*)(k + ((size_t)bh * 1024 + n) * 96 + dh) = v;
  } else {
#pragma unroll
    for (int e = 0; e < 8; e++)
      vt[((size_t)bh * 96 + dh + e) * 1024 + n] = v[e];
  }
}

// ---------------- GEMM: C(MxN) = A(MxK) @ Bt(NxK)^T, bf16 in, fp32 acc --------
// 128x128 tile, BK=32, 4 waves of 64x64, 16x16x32 MFMA, global_load_lds w16,
// XOR-swizzled LDS chunk layout (chunk c of row r stored at c ^ ((r>>1)&3)).
template <int EPI>  // 0: bf16 out; 1: +bias+resid f32; 2: +bias gelu bf16; 3: +bias gelu +resid f32
__global__ __launch_bounds__(256) void gemm_bt_kernel(
    const bf16* __restrict__ A, const bf16* __restrict__ Bt, int M, int Nn,
    int K, const float* __restrict__ bias, const float* __restrict__ resid,
    bf16* __restrict__ outb, float* __restrict__ outf) {
  __shared__ __align__(16) bf16 As[128 * 32];
  __shared__ __align__(16) bf16 Bs[128 * 32];
  int tid = threadIdx.x;
  int wave = tid >> 6, lane = tid & 63;
  int qd = lane >> 4, lr = lane & 15;
  int bm0 = blockIdx.y * 128, bn0 = blockIdx.x * 128;
  int wm = (wave >> 1) * 64, wn = (wave & 1) * 64;

  f32x4 acc[4][4] = {};

  // staging: lane fetches global chunk (row = lane>>2, col = (lane&3)^key)
  int srow = lane >> 2;
  int scol = ((lane & 3) ^ ((lane >> 3) & 3)) * 8;  // key = ((row%16)>>1)&3
  const bf16* Ag = A + (size_t)(bm0 + wave * 32 + srow) * K + scol;
  const bf16* Ag2 = Ag + (size_t)16 * K;
  const bf16* Bg = Bt + (size_t)(bn0 + wave * 32 + srow) * K + scol;
  const bf16* Bg2 = Bg + (size_t)16 * K;
  char* Al = (char*)As + wave * 2048;
  char* Bl = (char*)Bs + wave * 2048;
  int rk = (lr >> 1) & 3;  // read-side swizzle key

  for (int k0 = 0; k0 < K; k0 += 32) {
    gld_lds16(Ag + k0, Al);
    gld_lds16(Ag2 + k0, Al + 1024);
    gld_lds16(Bg + k0, Bl);
    gld_lds16(Bg2 + k0, Bl + 1024);
    __syncthreads();
    bf16x8 af[4], bfv[4];
#pragma unroll
    for (int i = 0; i < 4; i++)
      af[i] = *(const bf16x8*)&As[(wm + i * 16 + lr) * 32 + ((qd ^ rk) * 8)];
#pragma unroll
    for (int j = 0; j < 4; j++)
      bfv[j] = *(const bf16x8*)&Bs[(wn + j * 16 + lr) * 32 + ((qd ^ rk) * 8)];
#pragma unroll
    for (int i = 0; i < 4; i++)
#pragma unroll
      for (int j = 0; j < 4; j++)
        acc[i][j] = __builtin_amdgcn_mfma_f32_16x16x32_bf16(af[i], bfv[j],
                                                            acc[i][j], 0, 0, 0);
    __syncthreads();
  }

#pragma unroll
  for (int i = 0; i < 4; i++) {
#pragma unroll
    for (int j = 0; j < 4; j++) {
#pragma unroll
      for (int r = 0; r < 4; r++) {
        int row = bm0 + wm + i * 16 + qd * 4 + r;
        int col = bn0 + wn + j * 16 + lr;
        size_t o = (size_t)row * Nn + col;
        float v = acc[i][j][r];
        if (EPI == 0) {
          outb[o] = (bf16)v;
        } else if (EPI == 1) {
          outf[o] = v + bias[col] + resid[o];
        } else if (EPI == 2) {
          outb[o] = (bf16)gelu_f(v + bias[col]);
        } else {
          outf[o] = gelu_f(v + bias[col]) + resid[o];
        }
      }
    }
  }
}

// ---------------- fused attention, 128 q-rows/block, 64-key tiles -------------
// q,k: [bh][1024][96] bf16; vt: [bh][96][1024] bf16; out: permuted reshape.
__global__ __launch_bounds__(256) void attn_kernel(
    const bf16* __restrict__ qb, const bf16* __restrict__ kb,
    const bf16* __restrict__ vtb, bf16* __restrict__ operm) {
  __shared__ __align__(16) bf16 Ks[64 * 104];   // [key][dh], pad 104
  __shared__ __align__(16) bf16 Vs[96 * 72];    // [dh][key], pad 72
  __shared__ __align__(16) bf16 Ps[128 * 72];   // [qrow][key], pad 72
  int t = threadIdx.x;
  int w = t >> 6, lane = t & 63;
  int qd = lane >> 4, lr = lane & 15;
  int bh = blockIdx.y, nt0 = blockIdx.x * 128;
  int bq = bh >> 3, hh = bh & 7;

  // Q fragments pinned in registers (wave's 32 rows x 96 dh)
  const bf16* qg = qb + ((size_t)bh * 1024 + nt0 + w * 32) * 96;
  bf16x8 afq[2][3];
#pragma unroll
  for (int i = 0; i < 2; i++)
#pragma unroll
    for (int ks = 0; ks < 3; ks++)
      afq[i][ks] = *(const bf16x8*)(qg + (i * 16 + lr) * 96 + ks * 32 + qd * 8);

  f32x4 oacc[2][6] = {};
  float mst[2][4], lst[2][4];
#pragma unroll
  for (int i = 0; i < 2; i++)
#pragma unroll
    for (int r = 0; r < 4; r++) { mst[i][r] = -1e30f; lst[i][r] = 0.f; }

  const bf16* kgb = kb + (size_t)bh * 1024 * 96;
  const bf16* vgb = vtb + (size_t)bh * 96 * 1024;

  for (int kt = 0; kt < 16; kt++) {
    int k0 = kt * 64;
    const bf16* kg = kgb + (size_t)k0 * 96;
    const bf16* vg = vgb + k0;
#pragma unroll
    for (int it = 0; it < 3; it++) {
      int idx = it * 256 + t;
      int kr = idx / 12, c8 = idx % 12;
      *(bf16x8*)&Ks[kr * 104 + c8 * 8] = *(const bf16x8*)(kg + kr * 96 + c8 * 8);
    }
#pragma unroll
    for (int it = 0; it < 3; it++) {
      int idx = it * 256 + t;
      int dh = idx >> 3, c8 = idx & 7;
      *(bf16x8*)&Vs[dh * 72 + c8 * 8] =
          *(const bf16x8*)(vg + (size_t)dh * 1024 + c8 * 8);
    }
    __syncthreads();

    // S = Q @ K^T (wave strip: 32 q-rows x 64 keys)
    f32x4 sacc[2][4] = {};
#pragma unroll
    for (int ks = 0; ks < 3; ks++) {
      bf16x8 bk[4];
#pragma unroll
      for (int jn = 0; jn < 4; jn++)
        bk[jn] = *(const bf16x8*)&Ks[(jn * 16 + lr) * 104 + ks * 32 + qd * 8];
#pragma unroll
      for (int i = 0; i < 2; i++)
#pragma unroll
        for (int jn = 0; jn < 4; jn++)
          sacc[i][jn] = __builtin_amdgcn_mfma_f32_16x16x32_bf16(
              afq[i][ks], bk[jn], sacc[i][jn], 0, 0, 0);
    }
#pragma unroll
    for (int i = 0; i < 2; i++)
#pragma unroll
      for (int jn = 0; jn < 4; jn++) sacc[i][jn] *= SCALE_;

    // online softmax (row = qd*4 + r within 16; reduce over 16 lanes = cols)
#pragma unroll
    for (int i = 0; i < 2; i++) {
#pragma unroll
      for (int r = 0; r < 4; r++) {
        float mx = -1e30f;
#pragma unroll
        for (int jn = 0; jn < 4; jn++) mx = fmaxf(mx, sacc[i][jn][r]);
#pragma unroll
        for (int off = 1; off < 16; off <<= 1)
          mx = fmaxf(mx, __shfl_xor(mx, off));
        float mnew = fmaxf(mst[i][r], mx);
        float alpha = __expf(mst[i][r] - mnew);
        float rs = 0.f;
#pragma unroll
        for (int jn = 0; jn < 4; jn++) {
          float p = __expf(sacc[i][jn][r] - mnew);
          sacc[i][jn][r] = p;
          rs += p;
        }
#pragma unroll
        for (int off = 1; off < 16; off <<= 1) rs += __shfl_xor(rs, off);
        lst[i][r] = lst[i][r] * alpha + rs;
        mst[i][r] = mnew;
#pragma unroll
        for (int jn = 0; jn < 6; jn++) oacc[i][jn][r] *= alpha;
      }
    }
    // P: C-layout -> LDS (A-layout readback below)
#pragma unroll
    for (int i = 0; i < 2; i++)
#pragma unroll
      for (int jn = 0; jn < 4; jn++)
#pragma unroll
        for (int r = 0; r < 4; r++)
          Ps[(w * 32 + i * 16 + qd * 4 + r) * 72 + jn * 16 + lr] =
              (bf16)sacc[i][jn][r];
    __syncthreads();

    // O += P @ V
#pragma unroll
    for (int ks = 0; ks < 2; ks++) {
      bf16x8 ap[2];
#pragma unroll
      for (int i = 0; i < 2; i++)
        ap[i] = *(const bf16x8*)&Ps[(w * 32 + i * 16 + lr) * 72 + ks * 32 + qd * 8];
#pragma unroll
      for (int jn = 0; jn < 6; jn++) {
        bf16x8 bv = *(const bf16x8*)&Vs[(jn * 16 + lr) * 72 + ks * 32 + qd * 8];
#pragma unroll
        for (int i = 0; i < 2; i++)
          oacc[i][jn] = __builtin_amdgcn_mfma_f32_16x16x32_bf16(ap[i], bv,
                                                               oacc[i][jn], 0, 0, 0);
      }
    }
    __syncthreads();
  }

  // write with the reference's faithful (buggy) reshape:
  // o[b,h,n,dh] -> operm[b, h*128 + n/8, 96*(n%8) + dh]
#pragma unroll
  for (int i = 0; i < 2; i++) {
#pragma unroll
    for (int r = 0; r < 4; r++) {
      float inv = 1.0f / lst[i][r];
      int n = nt0 + w * 32 + i * 16 + qd * 4 + r;
      size_t rowo = (size_t)bq * 1024 + hh * 128 + (n >> 3);
      int colb = 96 * (n & 7);
#pragma unroll
      for (int jn = 0; jn < 6; jn++)
        operm[rowo * 768 + colb + jn * 16 + lr] =
            (bf16)(oacc[i][jn][r] * inv);
    }
  }
}

// ------------------------------------------------------------------------------
extern "C" void kernel_launch(void* const* d_in, const int* in_sizes, int n_in,
                              void* d_out, int out_size, void* d_ws,
                              size_t ws_size, hipStream_t stream) {
  const float* x = (const float*)d_in[0];
  const float* w_qkv = (const float*)d_in[1];
  const float* w_o = (const float*)d_in[2];
  const float* b_o = (const float*)d_in[3];
  const float* w1 = (const float*)d_in[4];
  const float* b1 = (const float*)d_in[5];
  const float* w2 = (const float*)d_in[6];
  const float* b2 = (const float*)d_in[7];
  const float* g1 = (const float*)d_in[8];
  const float* be1 = (const float*)d_in[9];
  const float* gm = (const float*)d_in[10];
  const float* bm = (const float*)d_in[11];
  const float* g3 = (const float*)d_in[12];
  const float* be3 = (const float*)d_in[13];

  char* ws = (char*)d_ws;
  size_t off = 0;
  auto alloc = [&](size_t bytes) {
    char* p = ws + off;
    off += (bytes + 255) & ~(size_t)255;
    return p;
  };
  bf16* wqkvT = (bf16*)alloc((size_t)2304 * 768 * 2);
  bf16* woT = (bf16*)alloc((size_t)768 * 768 * 2);
  bf16* w1T = (bf16*)alloc((size_t)3072 * 768 * 2);
  bf16* w2T = (bf16*)alloc((size_t)768 * 3072 * 2);
  bf16* hA = (bf16*)alloc((size_t)M_TOK * 768 * 2);     // LN1 out; reused: operm, h2
  bf16* qkv = (bf16*)alloc((size_t)M_TOK * 2304 * 2);   // reused: x3 (f32)
  bf16* qb = (bf16*)alloc((size_t)64 * 1024 * 96 * 2);
  bf16* kbuf = (bf16*)alloc((size_t)64 * 1024 * 96 * 2);
  bf16* vtb = (bf16*)alloc((size_t)64 * 96 * 1024 * 2);
  float* x2 = (float*)alloc((size_t)M_TOK * 768 * 4);
  bf16* a1 = (bf16*)alloc((size_t)M_TOK * 3072 * 2);
  bf16* operm = hA;
  bf16* h2 = hA;
  float* x3 = (float*)qkv;

  dim3 tb(32, 8);
  transpose_cast_kernel<<<dim3(72, 24), tb, 0, stream>>>(w_qkv, wqkvT, 768, 2304);
  transpose_cast_kernel<<<dim3(24, 24), tb, 0, stream>>>(w_o, woT, 768, 768);
  transpose_cast_kernel<<<dim3(96, 24), tb, 0, stream>>>(w1, w1T, 768, 3072);
  transpose_cast_kernel<<<dim3(24, 96), tb, 0, stream>>>(w2, w2T, 3072, 768);

  ln_kernel<1><<<M_TOK / 4, 256, 0, stream>>>(x, g1, be1, hA, nullptr);

  gemm_bt_kernel<0><<<dim3(18, 64), 256, 0, stream>>>(
      hA, wqkvT, M_TOK, 2304, 768, nullptr, nullptr, qkv, nullptr);

  split_qkv_kernel<<<(M_TOK * 288) / 256, 256, 0, stream>>>(qkv, qb, kbuf, vtb);

  attn_kernel<<<dim3(8, 64), 256, 0, stream>>>(qb, kbuf, vtb, operm);

  gemm_bt_kernel<1><<<dim3(6, 64), 256, 0, stream>>>(
      operm, woT, M_TOK, 768, 768, b_o, x, nullptr, x2);

  ln_kernel<1><<<M_TOK / 4, 256, 0, stream>>>(x2, gm, bm, h2, nullptr);

  gemm_bt_kernel<2><<<dim3(24, 64), 256, 0, stream>>>(
      h2, w1T, M_TOK, 3072, 768, b1, nullptr, a1, nullptr);

  gemm_bt_kernel<3><<<dim3(6, 64), 256, 0, stream>>>(
      a1, w2T, M_TOK, 768, 3072, b2, x2, nullptr, x3);

  ln_kernel<0><<<M_TOK / 4, 256, 0, stream>>>(x3, g3, be3, nullptr,
                                              (float*)d_out);
}

// Round 2
// 449.473 us; speedup vs baseline: 1.1434x; 1.1434x over previous
//
#include <hip/hip_runtime.h>
#include <cmath>
#include <cstdint>

typedef __bf16 bf16;
typedef __bf16 bf16x8 __attribute__((ext_vector_type(8)));
typedef __bf16 bf16x4 __attribute__((ext_vector_type(4)));
typedef float  f32x4  __attribute__((ext_vector_type(4)));

#define M_TOK 8192
#define SCALE_ 0.10206207261596575f   // 96^-0.5

__device__ __forceinline__ void gld_lds16(const void* g, void* l) {
  __builtin_amdgcn_global_load_lds(
      (__attribute__((address_space(1))) void*)(uintptr_t)g,
      (__attribute__((address_space(3))) void*)(uintptr_t)l,
      16, 0, 0);
}

__device__ __forceinline__ float gelu_f(float x) {
  return 0.5f * x * (1.0f + erff(x * 0.7071067811865475f));
}

// ---------------- weight transpose + cast: w (K x N f32) -> wt (N x K bf16) ----
__global__ __launch_bounds__(256) void transpose_cast_kernel(
    const float* __restrict__ w, bf16* __restrict__ wt, int K, int N) {
  __shared__ float tile[32][33];
  int tx = threadIdx.x, ty = threadIdx.y;
  int nt = blockIdx.x * 32, kt = blockIdx.y * 32;
#pragma unroll
  for (int i = ty; i < 32; i += 8)
    tile[i][tx] = w[(size_t)(kt + i) * N + nt + tx];
  __syncthreads();
#pragma unroll
  for (int i = ty; i < 32; i += 8)
    wt[(size_t)(nt + i) * K + kt + tx] = (bf16)tile[tx][i];
}

// ---------------- layernorm (f32 in -> bf16 out), one wave per row ------------
__global__ __launch_bounds__(256) void ln_kernel(
    const float* __restrict__ x, const float* __restrict__ g,
    const float* __restrict__ b, bf16* __restrict__ ob) {
  int w = threadIdx.x >> 6, lane = threadIdx.x & 63;
  size_t row = (size_t)blockIdx.x * 4 + w;
  const float* xr = x + row * 768;
  float4 v[3];
  float s = 0.f, sq = 0.f;
#pragma unroll
  for (int k = 0; k < 3; k++) {
    v[k] = *(const float4*)(xr + (k * 64 + lane) * 4);
    s += v[k].x + v[k].y + v[k].z + v[k].w;
    sq += v[k].x * v[k].x + v[k].y * v[k].y + v[k].z * v[k].z + v[k].w * v[k].w;
  }
#pragma unroll
  for (int off = 32; off >= 1; off >>= 1) {
    s += __shfl_xor(s, off);
    sq += __shfl_xor(sq, off);
  }
  float mean = s * (1.f / 768.f);
  float rstd = rsqrtf(sq * (1.f / 768.f) - mean * mean + 1e-5f);
#pragma unroll
  for (int k = 0; k < 3; k++) {
    int c = (k * 64 + lane) * 4;
    float4 gg = *(const float4*)(g + c);
    float4 bb = *(const float4*)(b + c);
    bf16x4 pk = {(bf16)((v[k].x - mean) * rstd * gg.x + bb.x),
                 (bf16)((v[k].y - mean) * rstd * gg.y + bb.y),
                 (bf16)((v[k].z - mean) * rstd * gg.z + bb.z),
                 (bf16)((v[k].w - mean) * rstd * gg.w + bb.w)};
    *(bf16x4*)(ob + row * 768 + c) = pk;
  }
}

// ------- ln2_reduce: t = p0+p1+b_o+x(resid); x2=t (f32); h2 = LN(t) bf16 ------
__global__ __launch_bounds__(256) void ln2_reduce_kernel(
    const float* __restrict__ p, const float* __restrict__ bo,
    const float* __restrict__ xres, const float* __restrict__ g,
    const float* __restrict__ b, float* __restrict__ x2,
    bf16* __restrict__ h2) {
  int w = threadIdx.x >> 6, lane = threadIdx.x & 63;
  size_t row = (size_t)blockIdx.x * 4 + w;
  const float* p0 = p + row * 768;
  const float* p1 = p0 + (size_t)M_TOK * 768;
  const float* xr = xres + row * 768;
  float4 v[3];
  float s = 0.f, sq = 0.f;
#pragma unroll
  for (int k = 0; k < 3; k++) {
    int c = (k * 64 + lane) * 4;
    float4 a0 = *(const float4*)(p0 + c);
    float4 a1 = *(const float4*)(p1 + c);
    float4 bb = *(const float4*)(bo + c);
    float4 rr = *(const float4*)(xr + c);
    v[k].x = a0.x + a1.x + bb.x + rr.x;
    v[k].y = a0.y + a1.y + bb.y + rr.y;
    v[k].z = a0.z + a1.z + bb.z + rr.z;
    v[k].w = a0.w + a1.w + bb.w + rr.w;
    *(float4*)(x2 + row * 768 + c) = v[k];
    s += v[k].x + v[k].y + v[k].z + v[k].w;
    sq += v[k].x * v[k].x + v[k].y * v[k].y + v[k].z * v[k].z + v[k].w * v[k].w;
  }
#pragma unroll
  for (int off = 32; off >= 1; off >>= 1) {
    s += __shfl_xor(s, off);
    sq += __shfl_xor(sq, off);
  }
  float mean = s * (1.f / 768.f);
  float rstd = rsqrtf(sq * (1.f / 768.f) - mean * mean + 1e-5f);
#pragma unroll
  for (int k = 0; k < 3; k++) {
    int c = (k * 64 + lane) * 4;
    float4 gg = *(const float4*)(g + c);
    float4 bb = *(const float4*)(b + c);
    bf16x4 pk = {(bf16)((v[k].x - mean) * rstd * gg.x + bb.x),
                 (bf16)((v[k].y - mean) * rstd * gg.y + bb.y),
                 (bf16)((v[k].z - mean) * rstd * gg.z + bb.z),
                 (bf16)((v[k].w - mean) * rstd * gg.w + bb.w)};
    *(bf16x4*)(h2 + row * 768 + c) = pk;
  }
}

// ------- ln3_reduce: t = gelu(p0+p1+b2)+x2; out = LN(t) f32 -------------------
__global__ __launch_bounds__(256) void ln3_reduce_kernel(
    const float* __restrict__ p, const float* __restrict__ b2,
    const float* __restrict__ x2, const float* __restrict__ g,
    const float* __restrict__ b, float* __restrict__ out) {
  int w = threadIdx.x >> 6, lane = threadIdx.x & 63;
  size_t row = (size_t)blockIdx.x * 4 + w;
  const float* p0 = p + row * 768;
  const float* p1 = p0 + (size_t)M_TOK * 768;
  const float* xr = x2 + row * 768;
  float4 v[3];
  float s = 0.f, sq = 0.f;
#pragma unroll
  for (int k = 0; k < 3; k++) {
    int c = (k * 64 + lane) * 4;
    float4 a0 = *(const float4*)(p0 + c);
    float4 a1 = *(const float4*)(p1 + c);
    float4 bb = *(const float4*)(b2 + c);
    float4 rr = *(const float4*)(xr + c);
    v[k].x = gelu_f(a0.x + a1.x + bb.x) + rr.x;
    v[k].y = gelu_f(a0.y + a1.y + bb.y) + rr.y;
    v[k].z = gelu_f(a0.z + a1.z + bb.z) + rr.z;
    v[k].w = gelu_f(a0.w + a1.w + bb.w) + rr.w;
    s += v[k].x + v[k].y + v[k].z + v[k].w;
    sq += v[k].x * v[k].x + v[k].y * v[k].y + v[k].z * v[k].z + v[k].w * v[k].w;
  }
#pragma unroll
  for (int off = 32; off >= 1; off >>= 1) {
    s += __shfl_xor(s, off);
    sq += __shfl_xor(sq, off);
  }
  float mean = s * (1.f / 768.f);
  float rstd = rsqrtf(sq * (1.f / 768.f) - mean * mean + 1e-5f);
#pragma unroll
  for (int k = 0; k < 3; k++) {
    int c = (k * 64 + lane) * 4;
    float4 gg = *(const float4*)(g + c);
    float4 bb = *(const float4*)(b + c);
    float4 ov = {(v[k].x - mean) * rstd * gg.x + bb.x,
                 (v[k].y - mean) * rstd * gg.y + bb.y,
                 (v[k].z - mean) * rstd * gg.z + bb.z,
                 (v[k].w - mean) * rstd * gg.w + bb.w};
    *(float4*)(out + row * 768 + c) = ov;
  }
}

// ---------------- GEMM: C(MxN) = A(M x lda) @ Bt(N x ldb)^T over Ksl ----------
// 128x128 tile, BK=32, 4 waves, 16x16x32 MFMA, global_load_lds w16, XOR swizzle.
// blockIdx.z = K-slice (split-K); A/Bt advanced by z*Ksl, outf by z*M*Nn.
// EPI: 2 = +bias gelu -> bf16; 4 = fused qkv split; 5 = raw f32 partial.
template <int EPI>
__global__ __launch_bounds__(256) void gemm_bt_kernel(
    const bf16* __restrict__ A, const bf16* __restrict__ Bt, int M, int Nn,
    int lda, int ldb, int Ksl, const float* __restrict__ bias,
    bf16* __restrict__ outb, float* __restrict__ outf, bf16* __restrict__ qo,
    bf16* __restrict__ ko, bf16* __restrict__ vto) {
  __shared__ __align__(16) bf16 As[128 * 32];
  __shared__ __align__(16) bf16 Bs[128 * 32];
  int tid = threadIdx.x;
  int wave = tid >> 6, lane = tid & 63;
  int qd = lane >> 4, lr = lane & 15;
  int bm0 = blockIdx.y * 128, bn0 = blockIdx.x * 128;
  int wm = (wave >> 1) * 64, wn = (wave & 1) * 64;
  int kbase = blockIdx.z * Ksl;

  f32x4 acc[4][4] = {};

  int srow = lane >> 2;
  int scol = ((lane & 3) ^ ((lane >> 3) & 3)) * 8;  // xor-swizzled chunk
  const bf16* Ag = A + (size_t)(bm0 + wave * 32 + srow) * lda + kbase + scol;
  const bf16* Ag2 = Ag + (size_t)16 * lda;
  const bf16* Bg = Bt + (size_t)(bn0 + wave * 32 + srow) * ldb + kbase + scol;
  const bf16* Bg2 = Bg + (size_t)16 * ldb;
  char* Al = (char*)As + wave * 2048;
  char* Bl = (char*)Bs + wave * 2048;
  int rk = (lr >> 1) & 3;  // read-side swizzle key

  for (int k0 = 0; k0 < Ksl; k0 += 32) {
    gld_lds16(Ag + k0, Al);
    gld_lds16(Ag2 + k0, Al + 1024);
    gld_lds16(Bg + k0, Bl);
    gld_lds16(Bg2 + k0, Bl + 1024);
    __syncthreads();
    bf16x8 af[4], bfv[4];
#pragma unroll
    for (int i = 0; i < 4; i++)
      af[i] = *(const bf16x8*)&As[(wm + i * 16 + lr) * 32 + ((qd ^ rk) * 8)];
#pragma unroll
    for (int j = 0; j < 4; j++)
      bfv[j] = *(const bf16x8*)&Bs[(wn + j * 16 + lr) * 32 + ((qd ^ rk) * 8)];
#pragma unroll
    for (int i = 0; i < 4; i++)
#pragma unroll
      for (int j = 0; j < 4; j++)
        acc[i][j] = __builtin_amdgcn_mfma_f32_16x16x32_bf16(af[i], bfv[j],
                                                            acc[i][j], 0, 0, 0);
    __syncthreads();
  }

  float* outfs = (EPI == 5) ? outf + (size_t)blockIdx.z * M * Nn : outf;

#pragma unroll
  for (int i = 0; i < 4; i++) {
#pragma unroll
    for (int j = 0; j < 4; j++) {
      if (EPI == 4) {
        // fused qkv split (Nn==2304). 16-col tiles never straddle head bounds.
        int colt = bn0 + wn + j * 16;
        int which = colt / 768;
        int rem = colt - which * 768;
        int h = rem / 96;
        int dhb = rem - h * 96;
        int row0 = bm0 + wm + i * 16 + qd * 4;
        int b = row0 >> 10, n0 = row0 & 1023;
        int bh = b * 8 + h;
        if (which == 2) {
          bf16x4 pk = {(bf16)acc[i][j][0], (bf16)acc[i][j][1],
                       (bf16)acc[i][j][2], (bf16)acc[i][j][3]};
          *(bf16x4*)(vto + ((size_t)(bh * 96 + dhb + lr)) * 1024 + n0) = pk;
        } else {
          bf16* dst = (which == 0) ? qo : ko;
#pragma unroll
          for (int r = 0; r < 4; r++)
            dst[((size_t)bh * 1024 + n0 + r) * 96 + dhb + lr] =
                (bf16)acc[i][j][r];
        }
      } else {
#pragma unroll
        for (int r = 0; r < 4; r++) {
          int row = bm0 + wm + i * 16 + qd * 4 + r;
          int col = bn0 + wn + j * 16 + lr;
          size_t o = (size_t)row * Nn + col;
          float v = acc[i][j][r];
          if (EPI == 2) {
            outb[o] = (bf16)gelu_f(v + bias[col]);
          } else {  // EPI == 5
            outfs[o] = v;
          }
        }
      }
    }
  }
}

// ---------------- fused attention, 128 q-rows/block, 64-key tiles -------------
__global__ __launch_bounds__(256) void attn_kernel(
    const bf16* __restrict__ qb, const bf16* __restrict__ kb,
    const bf16* __restrict__ vtb, bf16* __restrict__ operm) {
  __shared__ __align__(16) bf16 Ks[64 * 104];   // [key][dh], pad 104
  __shared__ __align__(16) bf16 Vs[96 * 72];    // [dh][key], pad 72
  __shared__ __align__(16) bf16 Ps[128 * 72];   // [qrow][key], pad 72
  int t = threadIdx.x;
  int w = t >> 6, lane = t & 63;
  int qd = lane >> 4, lr = lane & 15;
  int bh = blockIdx.y, nt0 = blockIdx.x * 128;
  int bq = bh >> 3, hh = bh & 7;

  const bf16* qg = qb + ((size_t)bh * 1024 + nt0 + w * 32) * 96;
  bf16x8 afq[2][3];
#pragma unroll
  for (int i = 0; i < 2; i++)
#pragma unroll
    for (int ks = 0; ks < 3; ks++)
      afq[i][ks] = *(const bf16x8*)(qg + (i * 16 + lr) * 96 + ks * 32 + qd * 8);

  f32x4 oacc[2][6] = {};
  float mst[2][4], lst[2][4];
#pragma unroll
  for (int i = 0; i < 2; i++)
#pragma unroll
    for (int r = 0; r < 4; r++) { mst[i][r] = -1e30f; lst[i][r] = 0.f; }

  const bf16* kgb = kb + (size_t)bh * 1024 * 96;
  const bf16* vgb = vtb + (size_t)bh * 96 * 1024;

  for (int kt = 0; kt < 16; kt++) {
    int k0 = kt * 64;
    const bf16* kg = kgb + (size_t)k0 * 96;
    const bf16* vg = vgb + k0;
#pragma unroll
    for (int it = 0; it < 3; it++) {
      int idx = it * 256 + t;
      int kr = idx / 12, c8 = idx % 12;
      *(bf16x8*)&Ks[kr * 104 + c8 * 8] = *(const bf16x8*)(kg + kr * 96 + c8 * 8);
    }
#pragma unroll
    for (int it = 0; it < 3; it++) {
      int idx = it * 256 + t;
      int dh = idx >> 3, c8 = idx & 7;
      *(bf16x8*)&Vs[dh * 72 + c8 * 8] =
          *(const bf16x8*)(vg + (size_t)dh * 1024 + c8 * 8);
    }
    __syncthreads();

    f32x4 sacc[2][4] = {};
#pragma unroll
    for (int ks = 0; ks < 3; ks++) {
      bf16x8 bk[4];
#pragma unroll
      for (int jn = 0; jn < 4; jn++)
        bk[jn] = *(const bf16x8*)&Ks[(jn * 16 + lr) * 104 + ks * 32 + qd * 8];
#pragma unroll
      for (int i = 0; i < 2; i++)
#pragma unroll
        for (int jn = 0; jn < 4; jn++)
          sacc[i][jn] = __builtin_amdgcn_mfma_f32_16x16x32_bf16(
              afq[i][ks], bk[jn], sacc[i][jn], 0, 0, 0);
    }
#pragma unroll
    for (int i = 0; i < 2; i++)
#pragma unroll
      for (int jn = 0; jn < 4; jn++) sacc[i][jn] *= SCALE_;

#pragma unroll
    for (int i = 0; i < 2; i++) {
#pragma unroll
      for (int r = 0; r < 4; r++) {
        float mx = -1e30f;
#pragma unroll
        for (int jn = 0; jn < 4; jn++) mx = fmaxf(mx, sacc[i][jn][r]);
#pragma unroll
        for (int off = 1; off < 16; off <<= 1)
          mx = fmaxf(mx, __shfl_xor(mx, off));
        float mnew = fmaxf(mst[i][r], mx);
        float alpha = __expf(mst[i][r] - mnew);
        float rs = 0.f;
#pragma unroll
        for (int jn = 0; jn < 4; jn++) {
          float p = __expf(sacc[i][jn][r] - mnew);
          sacc[i][jn][r] = p;
          rs += p;
        }
#pragma unroll
        for (int off = 1; off < 16; off <<= 1) rs += __shfl_xor(rs, off);
        lst[i][r] = lst[i][r] * alpha + rs;
        mst[i][r] = mnew;
#pragma unroll
        for (int jn = 0; jn < 6; jn++) oacc[i][jn][r] *= alpha;
      }
    }
#pragma unroll
    for (int i = 0; i < 2; i++)
#pragma unroll
      for (int jn = 0; jn < 4; jn++)
#pragma unroll
        for (int r = 0; r < 4; r++)
          Ps[(w * 32 + i * 16 + qd * 4 + r) * 72 + jn * 16 + lr] =
              (bf16)sacc[i][jn][r];
    __syncthreads();

#pragma unroll
    for (int ks = 0; ks < 2; ks++) {
      bf16x8 ap[2];
#pragma unroll
      for (int i = 0; i < 2; i++)
        ap[i] = *(const bf16x8*)&Ps[(w * 32 + i * 16 + lr) * 72 + ks * 32 + qd * 8];
#pragma unroll
      for (int jn = 0; jn < 6; jn++) {
        bf16x8 bv = *(const bf16x8*)&Vs[(jn * 16 + lr) * 72 + ks * 32 + qd * 8];
#pragma unroll
        for (int i = 0; i < 2; i++)
          oacc[i][jn] = __builtin_amdgcn_mfma_f32_16x16x32_bf16(ap[i], bv,
                                                               oacc[i][jn], 0, 0, 0);
      }
    }
    __syncthreads();
  }

  // faithful (buggy) reshape: o[b,h,n,dh] -> operm[b, h*128 + n/8, 96*(n%8)+dh]
#pragma unroll
  for (int i = 0; i < 2; i++) {
#pragma unroll
    for (int r = 0; r < 4; r++) {
      float inv = 1.0f / lst[i][r];
      int n = nt0 + w * 32 + i * 16 + qd * 4 + r;
      size_t rowo = (size_t)bq * 1024 + hh * 128 + (n >> 3);
      int colb = 96 * (n & 7);
#pragma unroll
      for (int jn = 0; jn < 6; jn++)
        operm[rowo * 768 + colb + jn * 16 + lr] =
            (bf16)(oacc[i][jn][r] * inv);
    }
  }
}

// ------------------------------------------------------------------------------
extern "C" void kernel_launch(void* const* d_in, const int* in_sizes, int n_in,
                              void* d_out, int out_size, void* d_ws,
                              size_t ws_size, hipStream_t stream) {
  const float* x = (const float*)d_in[0];
  const float* w_qkv = (const float*)d_in[1];
  const float* w_o = (const float*)d_in[2];
  const float* b_o = (const float*)d_in[3];
  const float* w1 = (const float*)d_in[4];
  const float* b1 = (const float*)d_in[5];
  const float* w2 = (const float*)d_in[6];
  const float* b2 = (const float*)d_in[7];
  const float* g1 = (const float*)d_in[8];
  const float* be1 = (const float*)d_in[9];
  const float* gm = (const float*)d_in[10];
  const float* bm = (const float*)d_in[11];
  const float* g3 = (const float*)d_in[12];
  const float* be3 = (const float*)d_in[13];

  char* ws = (char*)d_ws;
  size_t off = 0;
  auto alloc = [&](size_t bytes) {
    char* p = ws + off;
    off += (bytes + 255) & ~(size_t)255;
    return p;
  };
  const size_t SZ_TOK_BF = (size_t)M_TOK * 768 * 2;   // 12.58 MB
  bf16* wqkvT = (bf16*)alloc((size_t)2304 * 768 * 2);
  bf16* woT = (bf16*)alloc((size_t)768 * 768 * 2);
  bf16* w1T = (bf16*)alloc((size_t)3072 * 768 * 2);
  bf16* w2T = (bf16*)alloc((size_t)768 * 3072 * 2);
  // contiguous span B..E = 4 * 12.58 MB, also reused as W2 split-K partials
  bf16* hA = (bf16*)alloc(SZ_TOK_BF);   // LN1 out; then operm; then h2
  bf16* qb = (bf16*)alloc(SZ_TOK_BF);
  bf16* kbuf = (bf16*)alloc(SZ_TOK_BF);
  bf16* vtb = (bf16*)alloc(SZ_TOK_BF);
  float* x2 = (float*)alloc((size_t)M_TOK * 768 * 4);
  // G: Wo split-K partials (2 x 25.17 MB f32) then a1 (bf16 8192x3072)
  char* G = alloc((size_t)M_TOK * 3072 * 2);
  bf16* operm = hA;
  bf16* h2 = hA;
  float* pWo = (float*)G;
  bf16* a1 = (bf16*)G;
  float* pW2 = (float*)hA;  // spans hA..vtb (50.33 MB), live after a1's last read

  dim3 tb(32, 8);
  transpose_cast_kernel<<<dim3(72, 24), tb, 0, stream>>>(w_qkv, wqkvT, 768, 2304);
  transpose_cast_kernel<<<dim3(24, 24), tb, 0, stream>>>(w_o, woT, 768, 768);
  transpose_cast_kernel<<<dim3(96, 24), tb, 0, stream>>>(w1, w1T, 768, 3072);
  transpose_cast_kernel<<<dim3(24, 96), tb, 0, stream>>>(w2, w2T, 3072, 768);

  ln_kernel<<<M_TOK / 4, 256, 0, stream>>>(x, g1, be1, hA);

  // QKV GEMM with fused head-split epilogue
  gemm_bt_kernel<4><<<dim3(18, 64), 256, 0, stream>>>(
      hA, wqkvT, M_TOK, 2304, 768, 768, 768, nullptr, nullptr, nullptr, qb,
      kbuf, vtb);

  attn_kernel<<<dim3(8, 64), 256, 0, stream>>>(qb, kbuf, vtb, operm);

  // Wo GEMM, split-K=2 (slices of 384) -> f32 partials in G
  gemm_bt_kernel<5><<<dim3(6, 64, 2), 256, 0, stream>>>(
      operm, woT, M_TOK, 768, 768, 768, 384, nullptr, nullptr, pWo, nullptr,
      nullptr, nullptr);

  ln2_reduce_kernel<<<M_TOK / 4, 256, 0, stream>>>(pWo, b_o, x, gm, bm, x2, h2);

  // W1 GEMM: bias + exact GELU -> bf16 a1
  gemm_bt_kernel<2><<<dim3(24, 64), 256, 0, stream>>>(
      h2, w1T, M_TOK, 3072, 768, 768, 768, b1, a1, nullptr, nullptr, nullptr,
      nullptr);

  // W2 GEMM, split-K=2 (slices of 1536) -> f32 partials spanning hA..vtb
  gemm_bt_kernel<5><<<dim3(6, 64, 2), 256, 0, stream>>>(
      a1, w2T, M_TOK, 768, 3072, 3072, 1536, nullptr, nullptr, pW2, nullptr,
      nullptr, nullptr);

  ln3_reduce_kernel<<<M_TOK / 4, 256, 0, stream>>>(pW2, b2, x2, g3, be3,
                                                   (float*)d_out);
}

// Round 3
// 416.721 us; speedup vs baseline: 1.2332x; 1.0786x over previous
//
#include <hip/hip_runtime.h>
#include <cmath>
#include <cstdint>

typedef __bf16 bf16;
typedef __bf16 bf16x8 __attribute__((ext_vector_type(8)));
typedef __bf16 bf16x4 __attribute__((ext_vector_type(4)));
typedef float  f32x4  __attribute__((ext_vector_type(4)));

#define M_TOK 8192
#define SCALE_ 0.10206207261596575f   // 96^-0.5

__device__ __forceinline__ void gld_lds16(const void* g, void* l) {
  __builtin_amdgcn_global_load_lds(
      (__attribute__((address_space(1))) void*)(uintptr_t)g,
      (__attribute__((address_space(3))) void*)(uintptr_t)l,
      16, 0, 0);
}

__device__ __forceinline__ float gelu_f(float x) {
  return 0.5f * x * (1.0f + erff(x * 0.7071067811865475f));
}

// ---------------- weight transpose + cast: w (K x N f32) -> wt (N x K bf16) ----
__global__ __launch_bounds__(256) void transpose_cast_kernel(
    const float* __restrict__ w, bf16* __restrict__ wt, int K, int N) {
  __shared__ float tile[32][33];
  int tx = threadIdx.x, ty = threadIdx.y;
  int nt = blockIdx.x * 32, kt = blockIdx.y * 32;
#pragma unroll
  for (int i = ty; i < 32; i += 8)
    tile[i][tx] = w[(size_t)(kt + i) * N + nt + tx];
  __syncthreads();
#pragma unroll
  for (int i = ty; i < 32; i += 8)
    wt[(size_t)(nt + i) * K + kt + tx] = (bf16)tile[tx][i];
}

// ---------------- layernorm (f32 in -> bf16 out), one wave per row ------------
__global__ __launch_bounds__(256) void ln_kernel(
    const float* __restrict__ x, const float* __restrict__ g,
    const float* __restrict__ b, bf16* __restrict__ ob) {
  int w = threadIdx.x >> 6, lane = threadIdx.x & 63;
  size_t row = (size_t)blockIdx.x * 4 + w;
  const float* xr = x + row * 768;
  float4 v[3];
  float s = 0.f, sq = 0.f;
#pragma unroll
  for (int k = 0; k < 3; k++) {
    v[k] = *(const float4*)(xr + (k * 64 + lane) * 4);
    s += v[k].x + v[k].y + v[k].z + v[k].w;
    sq += v[k].x * v[k].x + v[k].y * v[k].y + v[k].z * v[k].z + v[k].w * v[k].w;
  }
#pragma unroll
  for (int off = 32; off >= 1; off >>= 1) {
    s += __shfl_xor(s, off);
    sq += __shfl_xor(sq, off);
  }
  float mean = s * (1.f / 768.f);
  float rstd = rsqrtf(sq * (1.f / 768.f) - mean * mean + 1e-5f);
#pragma unroll
  for (int k = 0; k < 3; k++) {
    int c = (k * 64 + lane) * 4;
    float4 gg = *(const float4*)(g + c);
    float4 bb = *(const float4*)(b + c);
    bf16x4 pk = {(bf16)((v[k].x - mean) * rstd * gg.x + bb.x),
                 (bf16)((v[k].y - mean) * rstd * gg.y + bb.y),
                 (bf16)((v[k].z - mean) * rstd * gg.z + bb.z),
                 (bf16)((v[k].w - mean) * rstd * gg.w + bb.w)};
    *(bf16x4*)(ob + row * 768 + c) = pk;
  }
}

// ------- ln2_reduce: t = p0+p1+b_o+x(resid f32); x2=t (bf16); h2 = LN(t) bf16 -
__global__ __launch_bounds__(256) void ln2_reduce_kernel(
    const bf16* __restrict__ p, const float* __restrict__ bo,
    const float* __restrict__ xres, const float* __restrict__ g,
    const float* __restrict__ b, bf16* __restrict__ x2,
    bf16* __restrict__ h2) {
  int w = threadIdx.x >> 6, lane = threadIdx.x & 63;
  size_t row = (size_t)blockIdx.x * 4 + w;
  const bf16* p0 = p + row * 768;
  const bf16* p1 = p0 + (size_t)M_TOK * 768;
  const float* xr = xres + row * 768;
  float4 v[3];
  float s = 0.f, sq = 0.f;
#pragma unroll
  for (int k = 0; k < 3; k++) {
    int c = (k * 64 + lane) * 4;
    bf16x4 a0 = *(const bf16x4*)(p0 + c);
    bf16x4 a1 = *(const bf16x4*)(p1 + c);
    float4 bb = *(const float4*)(bo + c);
    float4 rr = *(const float4*)(xr + c);
    v[k].x = (float)a0[0] + (float)a1[0] + bb.x + rr.x;
    v[k].y = (float)a0[1] + (float)a1[1] + bb.y + rr.y;
    v[k].z = (float)a0[2] + (float)a1[2] + bb.z + rr.z;
    v[k].w = (float)a0[3] + (float)a1[3] + bb.w + rr.w;
    bf16x4 xo = {(bf16)v[k].x, (bf16)v[k].y, (bf16)v[k].z, (bf16)v[k].w};
    *(bf16x4*)(x2 + row * 768 + c) = xo;
    s += v[k].x + v[k].y + v[k].z + v[k].w;
    sq += v[k].x * v[k].x + v[k].y * v[k].y + v[k].z * v[k].z + v[k].w * v[k].w;
  }
#pragma unroll
  for (int off = 32; off >= 1; off >>= 1) {
    s += __shfl_xor(s, off);
    sq += __shfl_xor(sq, off);
  }
  float mean = s * (1.f / 768.f);
  float rstd = rsqrtf(sq * (1.f / 768.f) - mean * mean + 1e-5f);
#pragma unroll
  for (int k = 0; k < 3; k++) {
    int c = (k * 64 + lane) * 4;
    float4 gg = *(const float4*)(g + c);
    float4 bb = *(const float4*)(b + c);
    bf16x4 pk = {(bf16)((v[k].x - mean) * rstd * gg.x + bb.x),
                 (bf16)((v[k].y - mean) * rstd * gg.y + bb.y),
                 (bf16)((v[k].z - mean) * rstd * gg.z + bb.z),
                 (bf16)((v[k].w - mean) * rstd * gg.w + bb.w)};
    *(bf16x4*)(h2 + row * 768 + c) = pk;
  }
}

// ------- ln3_reduce: t = gelu(p0+p1+b2)+x2(bf16); out = LN(t) f32 -------------
__global__ __launch_bounds__(256) void ln3_reduce_kernel(
    const bf16* __restrict__ p, const float* __restrict__ b2,
    const bf16* __restrict__ x2, const float* __restrict__ g,
    const float* __restrict__ b, float* __restrict__ out) {
  int w = threadIdx.x >> 6, lane = threadIdx.x & 63;
  size_t row = (size_t)blockIdx.x * 4 + w;
  const bf16* p0 = p + row * 768;
  const bf16* p1 = p0 + (size_t)M_TOK * 768;
  const bf16* xr = x2 + row * 768;
  float4 v[3];
  float s = 0.f, sq = 0.f;
#pragma unroll
  for (int k = 0; k < 3; k++) {
    int c = (k * 64 + lane) * 4;
    bf16x4 a0 = *(const bf16x4*)(p0 + c);
    bf16x4 a1 = *(const bf16x4*)(p1 + c);
    float4 bb = *(const float4*)(b2 + c);
    bf16x4 rr = *(const bf16x4*)(xr + c);
    v[k].x = gelu_f((float)a0[0] + (float)a1[0] + bb.x) + (float)rr[0];
    v[k].y = gelu_f((float)a0[1] + (float)a1[1] + bb.y) + (float)rr[1];
    v[k].z = gelu_f((float)a0[2] + (float)a1[2] + bb.z) + (float)rr[2];
    v[k].w = gelu_f((float)a0[3] + (float)a1[3] + bb.w) + (float)rr[3];
    s += v[k].x + v[k].y + v[k].z + v[k].w;
    sq += v[k].x * v[k].x + v[k].y * v[k].y + v[k].z * v[k].z + v[k].w * v[k].w;
  }
#pragma unroll
  for (int off = 32; off >= 1; off >>= 1) {
    s += __shfl_xor(s, off);
    sq += __shfl_xor(sq, off);
  }
  float mean = s * (1.f / 768.f);
  float rstd = rsqrtf(sq * (1.f / 768.f) - mean * mean + 1e-5f);
#pragma unroll
  for (int k = 0; k < 3; k++) {
    int c = (k * 64 + lane) * 4;
    float4 gg = *(const float4*)(g + c);
    float4 bb = *(const float4*)(b + c);
    float4 ov = {(v[k].x - mean) * rstd * gg.x + bb.x,
                 (v[k].y - mean) * rstd * gg.y + bb.y,
                 (v[k].z - mean) * rstd * gg.z + bb.z,
                 (v[k].w - mean) * rstd * gg.w + bb.w};
    *(float4*)(out + row * 768 + c) = ov;
  }
}

// ---------------- GEMM: C(M_TOK x NN) = A @ Bt^T over KSL (compile-time geom) -
// 128x128 tile, BK=32, 4 waves, 16x16x32 MFMA, global_load_lds w16, XOR swizzle.
// blockIdx.z = K-slice (split-K); A/Bt advanced by z*KSL, partial out by z.
// EPI: 2 = +bias gelu -> bf16; 4 = fused qkv split; 5 = bf16 partial.
template <int EPI, int LDA, int LDB, int KSL, int NN>
__global__ __launch_bounds__(256) void gemm_bt_kernel(
    const bf16* __restrict__ A, const bf16* __restrict__ Bt,
    const float* __restrict__ bias, bf16* __restrict__ outb,
    bf16* __restrict__ qo, bf16* __restrict__ ko, bf16* __restrict__ vto) {
  __shared__ __align__(16) bf16 As[128 * 32];
  __shared__ __align__(16) bf16 Bs[128 * 32];
  int tid = threadIdx.x;
  int wave = tid >> 6, lane = tid & 63;
  int qd = lane >> 4, lr = lane & 15;
  int bm0 = blockIdx.y * 128, bn0 = blockIdx.x * 128;
  int wm = (wave >> 1) * 64, wn = (wave & 1) * 64;
  int kbase = blockIdx.z * KSL;

  f32x4 acc[4][4] = {};

  int srow = lane >> 2;
  int scol = ((lane & 3) ^ ((lane >> 3) & 3)) * 8;  // xor-swizzled chunk
  const bf16* Ag = A + (size_t)(bm0 + wave * 32 + srow) * LDA + kbase + scol;
  const bf16* Ag2 = Ag + (size_t)16 * LDA;
  const bf16* Bg = Bt + (size_t)(bn0 + wave * 32 + srow) * LDB + kbase + scol;
  const bf16* Bg2 = Bg + (size_t)16 * LDB;
  char* Al = (char*)As + wave * 2048;
  char* Bl = (char*)Bs + wave * 2048;
  int rk = (lr >> 1) & 3;  // read-side swizzle key

#pragma unroll 4
  for (int k0 = 0; k0 < KSL; k0 += 32) {
    gld_lds16(Ag + k0, Al);
    gld_lds16(Ag2 + k0, Al + 1024);
    gld_lds16(Bg + k0, Bl);
    gld_lds16(Bg2 + k0, Bl + 1024);
    __syncthreads();
    bf16x8 af[4], bfv[4];
#pragma unroll
    for (int i = 0; i < 4; i++)
      af[i] = *(const bf16x8*)&As[(wm + i * 16 + lr) * 32 + ((qd ^ rk) * 8)];
#pragma unroll
    for (int j = 0; j < 4; j++)
      bfv[j] = *(const bf16x8*)&Bs[(wn + j * 16 + lr) * 32 + ((qd ^ rk) * 8)];
#pragma unroll
    for (int i = 0; i < 4; i++)
#pragma unroll
      for (int j = 0; j < 4; j++)
        acc[i][j] = __builtin_amdgcn_mfma_f32_16x16x32_bf16(af[i], bfv[j],
                                                            acc[i][j], 0, 0, 0);
    __syncthreads();
  }

  bf16* outbs = (EPI == 5) ? outb + (size_t)blockIdx.z * M_TOK * NN : outb;

#pragma unroll
  for (int i = 0; i < 4; i++) {
#pragma unroll
    for (int j = 0; j < 4; j++) {
      if (EPI == 4) {
        // fused qkv split (NN==2304). 16-col tiles never straddle head bounds.
        int colt = bn0 + wn + j * 16;
        int which = colt / 768;
        int rem = colt - which * 768;
        int h = rem / 96;
        int dhb = rem - h * 96;
        int row0 = bm0 + wm + i * 16 + qd * 4;
        int b = row0 >> 10, n0 = row0 & 1023;
        int bh = b * 8 + h;
        if (which == 2) {
          bf16x4 pk = {(bf16)acc[i][j][0], (bf16)acc[i][j][1],
                       (bf16)acc[i][j][2], (bf16)acc[i][j][3]};
          *(bf16x4*)(vto + ((size_t)(bh * 96 + dhb + lr)) * 1024 + n0) = pk;
        } else {
          bf16* dst = (which == 0) ? qo : ko;
#pragma unroll
          for (int r = 0; r < 4; r++)
            dst[((size_t)bh * 1024 + n0 + r) * 96 + dhb + lr] =
                (bf16)acc[i][j][r];
        }
      } else {
#pragma unroll
        for (int r = 0; r < 4; r++) {
          int row = bm0 + wm + i * 16 + qd * 4 + r;
          int col = bn0 + wn + j * 16 + lr;
          size_t o = (size_t)row * NN + col;
          float v = acc[i][j][r];
          if (EPI == 2) {
            outbs[o] = (bf16)gelu_f(v + bias[col]);
          } else {  // EPI == 5
            outbs[o] = (bf16)v;
          }
        }
      }
    }
  }
}

// ---------------- fused attention, 128 q-rows/block, 64-key tiles -------------
__global__ __launch_bounds__(256) void attn_kernel(
    const bf16* __restrict__ qb, const bf16* __restrict__ kb,
    const bf16* __restrict__ vtb, bf16* __restrict__ operm) {
  __shared__ __align__(16) bf16 Ks[64 * 104];   // [key][dh], pad 104
  __shared__ __align__(16) bf16 Vs[96 * 72];    // [dh][key], pad 72
  __shared__ __align__(16) bf16 Ps[128 * 72];   // [qrow][key], pad 72
  int t = threadIdx.x;
  int w = t >> 6, lane = t & 63;
  int qd = lane >> 4, lr = lane & 15;
  int bh = blockIdx.y, nt0 = blockIdx.x * 128;
  int bq = bh >> 3, hh = bh & 7;

  const bf16* qg = qb + ((size_t)bh * 1024 + nt0 + w * 32) * 96;
  bf16x8 afq[2][3];
#pragma unroll
  for (int i = 0; i < 2; i++)
#pragma unroll
    for (int ks = 0; ks < 3; ks++)
      afq[i][ks] = *(const bf16x8*)(qg + (i * 16 + lr) * 96 + ks * 32 + qd * 8);

  f32x4 oacc[2][6] = {};
  float mst[2][4], lst[2][4];
#pragma unroll
  for (int i = 0; i < 2; i++)
#pragma unroll
    for (int r = 0; r < 4; r++) { mst[i][r] = -1e30f; lst[i][r] = 0.f; }

  const bf16* kgb = kb + (size_t)bh * 1024 * 96;
  const bf16* vgb = vtb + (size_t)bh * 96 * 1024;

  for (int kt = 0; kt < 16; kt++) {
    int k0 = kt * 64;
    const bf16* kg = kgb + (size_t)k0 * 96;
    const bf16* vg = vgb + k0;
#pragma unroll
    for (int it = 0; it < 3; it++) {
      int idx = it * 256 + t;
      int kr = idx / 12, c8 = idx % 12;
      *(bf16x8*)&Ks[kr * 104 + c8 * 8] = *(const bf16x8*)(kg + kr * 96 + c8 * 8);
    }
#pragma unroll
    for (int it = 0; it < 3; it++) {
      int idx = it * 256 + t;
      int dh = idx >> 3, c8 = idx & 7;
      *(bf16x8*)&Vs[dh * 72 + c8 * 8] =
          *(const bf16x8*)(vg + (size_t)dh * 1024 + c8 * 8);
    }
    __syncthreads();

    f32x4 sacc[2][4] = {};
#pragma unroll
    for (int ks = 0; ks < 3; ks++) {
      bf16x8 bk[4];
#pragma unroll
      for (int jn = 0; jn < 4; jn++)
        bk[jn] = *(const bf16x8*)&Ks[(jn * 16 + lr) * 104 + ks * 32 + qd * 8];
#pragma unroll
      for (int i = 0; i < 2; i++)
#pragma unroll
        for (int jn = 0; jn < 4; jn++)
          sacc[i][jn] = __builtin_amdgcn_mfma_f32_16x16x32_bf16(
              afq[i][ks], bk[jn], sacc[i][jn], 0, 0, 0);
    }
#pragma unroll
    for (int i = 0; i < 2; i++)
#pragma unroll
      for (int jn = 0; jn < 4; jn++) sacc[i][jn] *= SCALE_;

#pragma unroll
    for (int i = 0; i < 2; i++) {
#pragma unroll
      for (int r = 0; r < 4; r++) {
        float mx = -1e30f;
#pragma unroll
        for (int jn = 0; jn < 4; jn++) mx = fmaxf(mx, sacc[i][jn][r]);
#pragma unroll
        for (int off = 1; off < 16; off <<= 1)
          mx = fmaxf(mx, __shfl_xor(mx, off));
        float mnew = fmaxf(mst[i][r], mx);
        float alpha = __expf(mst[i][r] - mnew);
        float rs = 0.f;
#pragma unroll
        for (int jn = 0; jn < 4; jn++) {
          float p = __expf(sacc[i][jn][r] - mnew);
          sacc[i][jn][r] = p;
          rs += p;
        }
#pragma unroll
        for (int off = 1; off < 16; off <<= 1) rs += __shfl_xor(rs, off);
        lst[i][r] = lst[i][r] * alpha + rs;
        mst[i][r] = mnew;
#pragma unroll
        for (int jn = 0; jn < 6; jn++) oacc[i][jn][r] *= alpha;
      }
    }
#pragma unroll
    for (int i = 0; i < 2; i++)
#pragma unroll
      for (int jn = 0; jn < 4; jn++)
#pragma unroll
        for (int r = 0; r < 4; r++)
          Ps[(w * 32 + i * 16 + qd * 4 + r) * 72 + jn * 16 + lr] =
              (bf16)sacc[i][jn][r];
    __syncthreads();

#pragma unroll
    for (int ks = 0; ks < 2; ks++) {
      bf16x8 ap[2];
#pragma unroll
      for (int i = 0; i < 2; i++)
        ap[i] = *(const bf16x8*)&Ps[(w * 32 + i * 16 + lr) * 72 + ks * 32 + qd * 8];
#pragma unroll
      for (int jn = 0; jn < 6; jn++) {
        bf16x8 bv = *(const bf16x8*)&Vs[(jn * 16 + lr) * 72 + ks * 32 + qd * 8];
#pragma unroll
        for (int i = 0; i < 2; i++)
          oacc[i][jn] = __builtin_amdgcn_mfma_f32_16x16x32_bf16(ap[i], bv,
                                                               oacc[i][jn], 0, 0, 0);
      }
    }
    __syncthreads();
  }

  // faithful (buggy) reshape: o[b,h,n,dh] -> operm[b, h*128 + n/8, 96*(n%8)+dh]
#pragma unroll
  for (int i = 0; i < 2; i++) {
#pragma unroll
    for (int r = 0; r < 4; r++) {
      float inv = 1.0f / lst[i][r];
      int n = nt0 + w * 32 + i * 16 + qd * 4 + r;
      size_t rowo = (size_t)bq * 1024 + hh * 128 + (n >> 3);
      int colb = 96 * (n & 7);
#pragma unroll
      for (int jn = 0; jn < 6; jn++)
        operm[rowo * 768 + colb + jn * 16 + lr] =
            (bf16)(oacc[i][jn][r] * inv);
    }
  }
}

// ------------------------------------------------------------------------------
extern "C" void kernel_launch(void* const* d_in, const int* in_sizes, int n_in,
                              void* d_out, int out_size, void* d_ws,
                              size_t ws_size, hipStream_t stream) {
  const float* x = (const float*)d_in[0];
  const float* w_qkv = (const float*)d_in[1];
  const float* w_o = (const float*)d_in[2];
  const float* b_o = (const float*)d_in[3];
  const float* w1 = (const float*)d_in[4];
  const float* b1 = (const float*)d_in[5];
  const float* w2 = (const float*)d_in[6];
  const float* b2 = (const float*)d_in[7];
  const float* g1 = (const float*)d_in[8];
  const float* be1 = (const float*)d_in[9];
  const float* gm = (const float*)d_in[10];
  const float* bm = (const float*)d_in[11];
  const float* g3 = (const float*)d_in[12];
  const float* be3 = (const float*)d_in[13];

  char* ws = (char*)d_ws;
  size_t off = 0;
  auto alloc = [&](size_t bytes) {
    char* p = ws + off;
    off += (bytes + 255) & ~(size_t)255;
    return p;
  };
  const size_t SZ_TOK_BF = (size_t)M_TOK * 768 * 2;   // 12.58 MB
  bf16* wqkvT = (bf16*)alloc((size_t)2304 * 768 * 2);
  bf16* woT = (bf16*)alloc((size_t)768 * 768 * 2);
  bf16* w1T = (bf16*)alloc((size_t)3072 * 768 * 2);
  bf16* w2T = (bf16*)alloc((size_t)768 * 3072 * 2);
  // contiguous span hA..vtb, reused late as W2 bf16 split-K partials (2 slabs)
  bf16* hA = (bf16*)alloc(SZ_TOK_BF);   // LN1 out; then operm; then h2
  bf16* qb = (bf16*)alloc(SZ_TOK_BF);
  bf16* kbuf = (bf16*)alloc(SZ_TOK_BF);
  bf16* vtb = (bf16*)alloc(SZ_TOK_BF);
  bf16* x2 = (bf16*)alloc(SZ_TOK_BF);
  // G: Wo bf16 split-K partials (2 x 12.58 MB), then a1 (bf16 8192x3072)
  char* G = alloc((size_t)M_TOK * 3072 * 2);
  bf16* operm = hA;
  bf16* h2 = hA;
  bf16* pWo = (bf16*)G;
  bf16* a1 = (bf16*)G;
  bf16* pW2 = hA;  // spans hA+qb (2 x 12.58 MB), live after a1's last read

  dim3 tb(32, 8);
  transpose_cast_kernel<<<dim3(72, 24), tb, 0, stream>>>(w_qkv, wqkvT, 768, 2304);
  transpose_cast_kernel<<<dim3(24, 24), tb, 0, stream>>>(w_o, woT, 768, 768);
  transpose_cast_kernel<<<dim3(96, 24), tb, 0, stream>>>(w1, w1T, 768, 3072);
  transpose_cast_kernel<<<dim3(24, 96), tb, 0, stream>>>(w2, w2T, 3072, 768);

  ln_kernel<<<M_TOK / 4, 256, 0, stream>>>(x, g1, be1, hA);

  // QKV GEMM with fused head-split epilogue
  gemm_bt_kernel<4, 768, 768, 768, 2304><<<dim3(18, 64), 256, 0, stream>>>(
      hA, wqkvT, nullptr, nullptr, qb, kbuf, vtb);

  attn_kernel<<<dim3(8, 64), 256, 0, stream>>>(qb, kbuf, vtb, operm);

  // Wo GEMM, split-K=2 (slices of 384) -> bf16 partials in G
  gemm_bt_kernel<5, 768, 768, 384, 768><<<dim3(6, 64, 2), 256, 0, stream>>>(
      operm, woT, nullptr, pWo, nullptr, nullptr, nullptr);

  ln2_reduce_kernel<<<M_TOK / 4, 256, 0, stream>>>(pWo, b_o, x, gm, bm, x2, h2);

  // W1 GEMM: bias + exact GELU -> bf16 a1
  gemm_bt_kernel<2, 768, 768, 768, 3072><<<dim3(24, 64), 256, 0, stream>>>(
      h2, w1T, b1, a1, nullptr, nullptr, nullptr);

  // W2 GEMM, split-K=2 (slices of 1536) -> bf16 partials spanning hA+qb
  gemm_bt_kernel<5, 3072, 3072, 1536, 768><<<dim3(6, 64, 2), 256, 0, stream>>>(
      a1, w2T, nullptr, pW2, nullptr, nullptr, nullptr);

  ln3_reduce_kernel<<<M_TOK / 4, 256, 0, stream>>>(pW2, b2, x2, g3, be3,
                                                   (float*)d_out);
}